// Round 12
// baseline (347.454 us; speedup 1.0000x reference)
//
#include <hip/hip_runtime.h>
#include <cstdint>
#include <cstddef>

// ---------------------------------------------------------------------------
// Fine_Grain_Layer. f32 I/O, bf16 MFMA operands, f32 accumulate.
// R19 -> R20: single-variable graft: s_setprio(1) around edge_kernel's MFMA
// clusters (FRONT's 24-MFMA, BACK's 2x8-MFMA). Edge waves are barrier-free
// and fully desynced -- the regime where setprio measured +4-7% (attn m191);
// null only for barrier-lockstep (GEMM m190). R14 had setprio but was
// confounded by its lambda spill; this is the clean A/B.
// R19 post-mortem: flattened skew was re-serialized by the scheduler
// (VGPR stayed 72 -> xa..xd never co-resident); the R18/19 win was the
// batched index loads. Compile-time ILP is exhausted; runtime wave
// arbitration is the remaining lever.
// Champion lineage: R13 (372) -> R16 (357.4) -> R18/R19 (345.1/345.8).
// ~155 us of dur is the harness's 1 GiB poison fill (fixed floor).
// ---------------------------------------------------------------------------

typedef short bf16x8 __attribute__((ext_vector_type(8)));
typedef float floatx4 __attribute__((ext_vector_type(4)));

#define MFMA16(a, b, c) __builtin_amdgcn_mfma_f32_16x16x32_bf16((a), (b), (c), 0, 0, 0)

// DPP lane-move within 16-lane rows (VALU pipe, no LDS). ctrl must be literal.
#define DPPMV(x, ctrl) __builtin_bit_cast(float, __builtin_amdgcn_update_dpp( \
        0, __builtin_bit_cast(int, (x)), (ctrl), 0xF, 0xF, true))

__device__ __forceinline__ unsigned short f2bf(float f) {
    unsigned int u = __builtin_bit_cast(unsigned int, f);
    u += 0x7fffu + ((u >> 16) & 1u);   // round to nearest even
    return (unsigned short)(u >> 16);
}
__device__ __forceinline__ float bf2f(unsigned short u) {
    unsigned int x = ((unsigned int)u) << 16;
    return __builtin_bit_cast(float, x);
}
__device__ __forceinline__ bf16x8 cvt8(const float* __restrict__ p) {
    float4 v0 = *(const float4*)(p);
    float4 v1 = *(const float4*)(p + 4);
    bf16x8 r;
    r[0] = (short)f2bf(v0.x); r[1] = (short)f2bf(v0.y);
    r[2] = (short)f2bf(v0.z); r[3] = (short)f2bf(v0.w);
    r[4] = (short)f2bf(v1.x); r[5] = (short)f2bf(v1.y);
    r[6] = (short)f2bf(v1.z); r[7] = (short)f2bf(v1.w);
    return r;
}
// sum/max over each 16-lane group: quads, then cross-quad, then cross-8.
__device__ __forceinline__ float rowsum16(float x) {
    x += DPPMV(x, 0xB1);    // quad_perm [1,0,3,2]  (xor 1)
    x += DPPMV(x, 0x4E);    // quad_perm [2,3,0,1]  (xor 2)
    x += DPPMV(x, 0x141);   // row_half_mirror      (other quad in 8)
    x += DPPMV(x, 0x140);   // row_mirror           (other 8 in 16)
    return x;
}
__device__ __forceinline__ float rowmax16(float x) {
    x = fmaxf(x, DPPMV(x, 0xB1));
    x = fmaxf(x, DPPMV(x, 0x4E));
    x = fmaxf(x, DPPMV(x, 0x141));
    x = fmaxf(x, DPPMV(x, 0x140));
    return x;
}
__device__ __forceinline__ float lrelu(float x) { return x > 0.f ? x : 0.01f * x; }
__device__ __forceinline__ float ln_rstd(float s2, float mean) {
    float var = s2 * 0.015625f - mean * mean;
    return rsqrtf(fmaxf(var, 0.0f) + 1e-5f);
}

__constant__ float INVSIG[16] = {
    1.0f, 0.6666666865f, 0.4444444597f, 0.2962962985f, 0.1975308657f,
    0.1316872428f, 0.0877914950f, 0.0585276633f, 0.0390184447f, 0.0260122959f,
    0.0173415299f, 0.0115610203f, 0.0077073467f, 0.0051382311f, 0.0034254875f, 0.0f};

// ---------------------------------------------------------------------------
// Pre-convert h (2x524288) and ef (2x8388608) to bf16. Quad-granular.
__global__ void prep_kernel(const float* __restrict__ hA, const float* __restrict__ hB,
                            const float* __restrict__ efA, const float* __restrict__ efB,
                            unsigned short* __restrict__ hbA, unsigned short* __restrict__ hbB,
                            unsigned short* __restrict__ efbA, unsigned short* __restrict__ efbB)
{
    int q = blockIdx.x * 256 + threadIdx.x;   // 4,456,448 quads exactly
    const float* s; unsigned short* d; int off;
    if (q < 131072)        { s = hA;  d = hbA;  off = q; }
    else if (q < 262144)   { s = hB;  d = hbB;  off = q - 131072; }
    else if (q < 2359296)  { s = efA; d = efbA; off = q - 262144; }
    else                   { s = efB; d = efbB; off = q - 2359296; }
    float4 v = *(const float4*)(s + (size_t)off * 4);
    ushort4 o;
    o.x = f2bf(v.x); o.y = f2bf(v.y); o.z = f2bf(v.z); o.w = f2bf(v.w);
    *(ushort4*)(d + (size_t)off * 4) = o;
}

// ---------------------------------------------------------------------------
// Per-edge precompute: xr[e] (3 f32) and rbf row (16 bf16). Streaming.
__global__ void edgeprep_kernel(const float* __restrict__ coordsA, const int* __restrict__ srcA,
                                const int* __restrict__ dstA,
                                const float* __restrict__ coordsB, const int* __restrict__ srcB,
                                const int* __restrict__ dstB,
                                float* __restrict__ xrbA, float* __restrict__ xrbB,
                                unsigned short* __restrict__ rbfbA, unsigned short* __restrict__ rbfbB)
{
    int i = blockIdx.x * 256 + threadIdx.x;   // 524288 exactly
    int brB = i >= 262144;
    int e = i - (brB ? 262144 : 0);
    const float* coords = brB ? coordsB : coordsA;
    const int* src = brB ? srcB : srcA;
    const int* dst = brB ? dstB : dstA;
    float* xrb = brB ? xrbB : xrbA;
    unsigned short* rbfb = brB ? rbfbB : rbfbA;

    int s = src[e], d0 = dst[e];
    float xr0 = coords[s * 3 + 0] - coords[d0 * 3 + 0];
    float xr1 = coords[s * 3 + 1] - coords[d0 * 3 + 1];
    float xr2 = coords[s * 3 + 2] - coords[d0 * 3 + 2];
    float d2 = xr0 * xr0 + xr1 * xr1 + xr2 * xr2;
    xrb[(size_t)e * 3 + 0] = xr0;
    xrb[(size_t)e * 3 + 1] = xr1;
    xrb[(size_t)e * 3 + 2] = xr2;
    ushort4 o0, o1, o2, o3;
    unsigned short rv[16];
    #pragma unroll
    for (int j = 0; j < 15; j++) rv[j] = f2bf(__expf(-d2 * INVSIG[j]));
    rv[15] = 0;
    o0.x = rv[0];  o0.y = rv[1];  o0.z = rv[2];  o0.w = rv[3];
    o1.x = rv[4];  o1.y = rv[5];  o1.z = rv[6];  o1.w = rv[7];
    o2.x = rv[8];  o2.y = rv[9];  o2.z = rv[10]; o2.w = rv[11];
    o3.x = rv[12]; o3.y = rv[13]; o3.z = rv[14]; o3.w = rv[15];
    *(ushort4*)(rbfb + (size_t)e * 16)      = o0;
    *(ushort4*)(rbfb + (size_t)e * 16 + 4)  = o1;
    *(ushort4*)(rbfb + (size_t)e * 16 + 8)  = o2;
    *(ushort4*)(rbfb + (size_t)e * 16 + 12) = o3;
}

// ---------------------------------------------------------------------------
__global__ void hist_kernel(const int* __restrict__ dstA, const int* __restrict__ dstB,
                            int* __restrict__ histA, int* __restrict__ histB)
{
    int e = blockIdx.x * 256 + threadIdx.x;   // exactly 262144
    atomicAdd(&histA[dstA[e]], 1);
    atomicAdd(&histB[dstB[e]], 1);
}

__global__ void scan_kernel(const int* __restrict__ histA, const int* __restrict__ histB,
                            int* __restrict__ rowptrA, int* __restrict__ rowptrB)
{
    const int b = blockIdx.x;   // 0 = A, 1 = B
    const int* hist = b ? histB : histA;
    int* rowptr = b ? rowptrB : rowptrA;
    __shared__ int part[1024];
    int t = threadIdx.x;
    int v[8]; int s = 0;
    #pragma unroll
    for (int j = 0; j < 8; j++) { v[j] = hist[t * 8 + j]; s += v[j]; }
    part[t] = s;
    __syncthreads();
    for (int off = 1; off < 1024; off <<= 1) {
        int x = part[t];
        int y = (t >= off) ? part[t - off] : 0;
        __syncthreads();
        part[t] = x + y;
        __syncthreads();
    }
    int run = (t > 0) ? part[t - 1] : 0;
    #pragma unroll
    for (int j = 0; j < 8; j++) { rowptr[t * 8 + j] = run; run += v[j]; }
    if (t == 1023) rowptr[8192] = run;
}

// pos[e] = slot of edge e in dst-CSR order
__global__ void scatter_kernel(const int* __restrict__ dstA, const int* __restrict__ dstB,
                               const int* __restrict__ rowptrA, const int* __restrict__ rowptrB,
                               int* __restrict__ curA, int* __restrict__ curB,
                               int* __restrict__ posA, int* __restrict__ posB)
{
    int e = blockIdx.x * 256 + threadIdx.x;   // exactly 262144
    int dA = dstA[e];
    posA[e] = rowptrA[dA] + atomicAdd(&curA[dA], 1);
    int dB = dstB[e];
    posB[e] = rowptrB[dB] + atomicAdd(&curB[dB], 1);
}

// ---------------------------------------------------------------------------
// FRONT: gathers + layer1 MFMA + LN1 -> XOUT[4][4] (registers only).
// Braced block = fresh scoped locals per expansion (no captures).
#define EDGE_FRONT(HB, EFB, RBFB, EIDX, SV, DV, XOUT)                           \
    {                                                                           \
        bf16x8 f0 = *(const bf16x8*)((HB) + (size_t)(SV) * 64 + 8 * g);         \
        bf16x8 f1 = *(const bf16x8*)((HB) + (size_t)(SV) * 64 + 32 + 8 * g);    \
        bf16x8 f2 = *(const bf16x8*)((HB) + (size_t)(DV) * 64 + 8 * g);         \
        bf16x8 f3 = *(const bf16x8*)((HB) + (size_t)(DV) * 64 + 32 + 8 * g);    \
        bf16x8 f4 = *(const bf16x8*)((EFB) + (size_t)(EIDX) * 32 + 8 * g);      \
        bf16x8 f5 = (g < 2) ? *(const bf16x8*)((RBFB) + (size_t)(EIDX) * 16 + 8 * g) : (bf16x8)0; \
        floatx4 acc[4];                                                         \
        _Pragma("unroll") for (int t = 0; t < 4; t++) acc[t] = (floatx4)0.0f;   \
        __builtin_amdgcn_s_setprio(1);                                          \
        _Pragma("unroll") for (int t = 0; t < 4; t++) {                         \
            const short* wr = &Wt1[(t * 16 + l15) * 200 + 8 * g];               \
            acc[t] = MFMA16(f0, *(const bf16x8*)(wr),       acc[t]);            \
            acc[t] = MFMA16(f1, *(const bf16x8*)(wr + 32),  acc[t]);            \
            acc[t] = MFMA16(f2, *(const bf16x8*)(wr + 64),  acc[t]);            \
            acc[t] = MFMA16(f3, *(const bf16x8*)(wr + 96),  acc[t]);            \
            acc[t] = MFMA16(f4, *(const bf16x8*)(wr + 128), acc[t]);            \
            acc[t] = MFMA16(f5, *(const bf16x8*)(wr + 160), acc[t]);            \
        }                                                                       \
        __builtin_amdgcn_s_setprio(0);                                          \
        float vv[4][4];                                                         \
        _Pragma("unroll") for (int t = 0; t < 4; t++)                           \
            _Pragma("unroll") for (int r = 0; r < 4; r++) vv[t][r] = acc[t][r] + b1v[t]; \
        _Pragma("unroll") for (int r = 0; r < 4; r++) {                         \
            float s1 = vv[0][r] + vv[1][r] + vv[2][r] + vv[3][r];               \
            float s2 = vv[0][r] * vv[0][r] + vv[1][r] * vv[1][r] + vv[2][r] * vv[2][r] + vv[3][r] * vv[3][r]; \
            s1 = rowsum16(s1);                                                  \
            s2 = rowsum16(s2);                                                  \
            float mean = s1 * 0.015625f;                                        \
            float rstd = ln_rstd(s2, mean);                                     \
            _Pragma("unroll") for (int t = 0; t < 4; t++)                       \
                XOUT[t][r] = lrelu((vv[t][r] - mean) * rstd * g1v[t] + t1v[t]); \
        }                                                                       \
    }

// BACK: msgb round trips + layer2 + LN2 + CSR store + coef MLP + atomic.
#define EDGE_BACK(MSGBUF, XUP, XIN, SLOTV, DV, XRGV)                            \
    {                                                                           \
        _Pragma("unroll") for (int r = 0; r < 4; r++) {                         \
            int rowoff = (4 * g + r) * 72;                                      \
            _Pragma("unroll") for (int t = 0; t < 4; t++)                       \
                msgb[wave][rowoff + t * 16 + l15] = (short)f2bf(XIN[t][r]);     \
        }                                                                       \
        bf16x8 a20 = *(const bf16x8*)(&msgb[wave][l15 * 72 + 8 * g]);           \
        bf16x8 a21 = *(const bf16x8*)(&msgb[wave][l15 * 72 + 32 + 8 * g]);      \
        floatx4 acc2[4];                                                        \
        _Pragma("unroll") for (int t = 0; t < 4; t++) acc2[t] = (floatx4)0.0f;  \
        __builtin_amdgcn_s_setprio(1);                                          \
        _Pragma("unroll") for (int t = 0; t < 4; t++) {                         \
            const short* wr2 = &Wt2s[(t * 16 + l15) * 72 + 8 * g];              \
            acc2[t] = MFMA16(a20, *(const bf16x8*)(wr2),      acc2[t]);         \
            acc2[t] = MFMA16(a21, *(const bf16x8*)(wr2 + 32), acc2[t]);         \
        }                                                                       \
        __builtin_amdgcn_s_setprio(0);                                          \
        float vm[4][4];                                                         \
        _Pragma("unroll") for (int t = 0; t < 4; t++)                           \
            _Pragma("unroll") for (int r = 0; r < 4; r++) vm[t][r] = acc2[t][r] + b2v[t]; \
        _Pragma("unroll") for (int r = 0; r < 4; r++) {                         \
            float s1 = vm[0][r] + vm[1][r] + vm[2][r] + vm[3][r];               \
            float s2 = vm[0][r] * vm[0][r] + vm[1][r] * vm[1][r] + vm[2][r] * vm[2][r] + vm[3][r] * vm[3][r]; \
            s1 = rowsum16(s1);                                                  \
            s2 = rowsum16(s2);                                                  \
            float mean = s1 * 0.015625f;                                        \
            float rstd = ln_rstd(s2, mean);                                     \
            _Pragma("unroll") for (int t = 0; t < 4; t++)                       \
                vm[t][r] = (vm[t][r] - mean) * rstd * g2v[t] + t2v[t];          \
        }                                                                       \
        _Pragma("unroll") for (int r = 0; r < 4; r++) {                         \
            int rowoff = (4 * g + r) * 72;                                      \
            _Pragma("unroll") for (int t = 0; t < 4; t++)                       \
                msgb[wave][rowoff + t * 16 + l15] = (short)f2bf(vm[t][r]);      \
        }                                                                       \
        bf16x8 a30 = *(const bf16x8*)(&msgb[wave][l15 * 72 + 8 * g]);           \
        bf16x8 a31 = *(const bf16x8*)(&msgb[wave][l15 * 72 + 32 + 8 * g]);      \
        {                                                                       \
            unsigned short* mrow = (MSGBUF) + (size_t)(SLOTV) * 64;             \
            *(bf16x8*)(mrow + 8 * g)      = a30;                                \
            *(bf16x8*)(mrow + 32 + 8 * g) = a31;                                \
        }                                                                       \
        floatx4 acc3[4];                                                        \
        _Pragma("unroll") for (int t = 0; t < 4; t++) acc3[t] = (floatx4)0.0f;  \
        __builtin_amdgcn_s_setprio(1);                                          \
        _Pragma("unroll") for (int t = 0; t < 4; t++) {                         \
            const short* wr3 = &Wc1s[(t * 16 + l15) * 72 + 8 * g];              \
            acc3[t] = MFMA16(a30, *(const bf16x8*)(wr3),      acc3[t]);         \
            acc3[t] = MFMA16(a31, *(const bf16x8*)(wr3 + 32), acc3[t]);         \
        }                                                                       \
        __builtin_amdgcn_s_setprio(0);                                          \
        float w3[4][4];                                                         \
        _Pragma("unroll") for (int t = 0; t < 4; t++)                           \
            _Pragma("unroll") for (int r = 0; r < 4; r++) w3[t][r] = acc3[t][r] + c1v[t]; \
        float coefr[4];                                                         \
        _Pragma("unroll") for (int r = 0; r < 4; r++) {                         \
            float s1 = w3[0][r] + w3[1][r] + w3[2][r] + w3[3][r];               \
            float s2 = w3[0][r] * w3[0][r] + w3[1][r] * w3[1][r] + w3[2][r] * w3[2][r] + w3[3][r] * w3[3][r]; \
            s1 = rowsum16(s1);                                                  \
            s2 = rowsum16(s2);                                                  \
            float mean = s1 * 0.015625f;                                        \
            float rstd = ln_rstd(s2, mean);                                     \
            float p = 0.f;                                                      \
            _Pragma("unroll") for (int t = 0; t < 4; t++) {                     \
                float x = (w3[t][r] - mean) * rstd * cg1v[t] + ct1v[t];         \
                x = lrelu(x);                                                   \
                p += x * w2v[t];                                                \
            }                                                                   \
            p = rowsum16(p);                                                    \
            coefr[r] = p + cb2s;                                                \
        }                                                                       \
        int srcl = (l15 >> 2) << 4;                                             \
        float v0 = __shfl(coefr[0], srcl);                                      \
        float v1 = __shfl(coefr[1], srcl);                                      \
        float v2 = __shfl(coefr[2], srcl);                                      \
        float v3 = __shfl(coefr[3], srcl);                                      \
        int rsel = l15 & 3;                                                     \
        float cf = (rsel == 0) ? v0 : (rsel == 1) ? v1 : (rsel == 2) ? v2 : v3; \
        if (g < 3) {                                                            \
            atomicAdd(&(XUP)[(size_t)(DV) * 3 + g], (XRGV) * cf);               \
        }                                                                       \
    }

// Edge kernel: 4 groups per wave, skewed straight-line schedule
// F_a F_b B_a F_c B_b F_d B_c B_d (a,b = branch A; c,d = branch B).
__global__ __launch_bounds__(512, 2) void edge_kernel(
    const unsigned short* __restrict__ hbA,
    const unsigned short* __restrict__ efbA, const int* __restrict__ srcA,
    const int* __restrict__ dstA, const int* __restrict__ posA,
    const float* __restrict__ xrbA, const unsigned short* __restrict__ rbfbA,
    const unsigned short* __restrict__ hbB,
    const unsigned short* __restrict__ efbB, const int* __restrict__ srcB,
    const int* __restrict__ dstB, const int* __restrict__ posB,
    const float* __restrict__ xrbB, const unsigned short* __restrict__ rbfbB,
    const float* __restrict__ eW1, const float* __restrict__ eb1,
    const float* __restrict__ eg1, const float* __restrict__ ebt1,
    const float* __restrict__ eW2, const float* __restrict__ eb2,
    const float* __restrict__ eg2, const float* __restrict__ ebt2,
    const float* __restrict__ cW1, const float* __restrict__ cb1,
    const float* __restrict__ cg1, const float* __restrict__ cbt1,
    const float* __restrict__ cW2, const float* __restrict__ cb2,
    unsigned short* __restrict__ msgbufA, unsigned short* __restrict__ msgbufB,
    float* __restrict__ xupA, float* __restrict__ xupB)
{
    __shared__ __attribute__((aligned(16))) short Wt1[64 * 200];   // 25600 B
    __shared__ __attribute__((aligned(16))) short Wt2s[64 * 72];   //  9216 B
    __shared__ __attribute__((aligned(16))) short Wc1s[64 * 72];   //  9216 B
    __shared__ __attribute__((aligned(16))) short msgb[8][16 * 72];// 18432 B -> 62464 total

    const int tid = threadIdx.x;

    for (int i = tid; i < 64 * 192; i += 512) {
        int n = i / 192, kk = i - n * 192;
        Wt1[n * 200 + kk] = (kk < 175) ? (short)f2bf(eW1[kk * 64 + n]) : (short)0;
    }
    for (int i = tid; i < 4096; i += 512) {
        int n = i >> 6, kk = i & 63;
        Wt2s[n * 72 + kk] = (short)f2bf(eW2[kk * 64 + n]);
        Wc1s[n * 72 + kk] = (short)f2bf(cW1[kk * 64 + n]);
    }

    const int wave = tid >> 6;
    const int lane = tid & 63;
    const int l15 = lane & 15;
    const int g = lane >> 4;

    // loop-invariant per-lane bias/gain registers (colx = t*16+l15)
    float b1v[4], g1v[4], t1v[4], b2v[4], g2v[4], t2v[4];
    float c1v[4], cg1v[4], ct1v[4], w2v[4];
    #pragma unroll
    for (int t = 0; t < 4; t++) {
        int colx = t * 16 + l15;
        b1v[t] = eb1[colx];  g1v[t] = eg1[colx];  t1v[t] = ebt1[colx];
        b2v[t] = eb2[colx];  g2v[t] = eg2[colx];  t2v[t] = ebt2[colx];
        c1v[t] = cb1[colx];  cg1v[t] = cg1[colx]; ct1v[t] = cbt1[colx];
        w2v[t] = cW2[colx];
    }
    const float cb2s = cb2[0];

    __syncthreads();   // the ONLY barrier

    const int wv = blockIdx.x * 8 + wave;   // 0..8191
    const int ei0 = wv * 16 + l15;          // groups a (A) / c (B)
    const int ei1 = (wv + 8192) * 16 + l15; // groups b (A) / d (B)

    // all index + xr loads batched up front (16 independent loads)
    const int s_a = srcA[ei0], d_a = dstA[ei0], p_a = posA[ei0];
    const int s_b = srcA[ei1], d_b = dstA[ei1], p_b = posA[ei1];
    const int s_c = srcB[ei0], d_c = dstB[ei0], p_c = posB[ei0];
    const int s_d = srcB[ei1], d_d = dstB[ei1], p_d = posB[ei1];
    const float xr_a = (g < 3) ? xrbA[(size_t)ei0 * 3 + g] : 0.0f;
    const float xr_b = (g < 3) ? xrbA[(size_t)ei1 * 3 + g] : 0.0f;
    const float xr_c = (g < 3) ? xrbB[(size_t)ei0 * 3 + g] : 0.0f;
    const float xr_d = (g < 3) ? xrbB[(size_t)ei1 * 3 + g] : 0.0f;

    float xa[4][4], xb[4][4], xc[4][4], xd[4][4];
    EDGE_FRONT(hbA, efbA, rbfbA, ei0, s_a, d_a, xa);
    EDGE_FRONT(hbA, efbA, rbfbA, ei1, s_b, d_b, xb);
    EDGE_BACK (msgbufA, xupA, xa, p_a, d_a, xr_a);
    EDGE_FRONT(hbB, efbB, rbfbB, ei0, s_c, d_c, xc);
    EDGE_BACK (msgbufA, xupA, xb, p_b, d_b, xr_b);
    EDGE_FRONT(hbB, efbB, rbfbB, ei1, s_d, d_d, xd);
    EDGE_BACK (msgbufB, xupB, xc, p_c, d_c, xr_c);
    EDGE_BACK (msgbufB, xupB, xd, p_d, d_d, xr_d);
}

// ---------------------------------------------------------------------------
// Gather-reduce over CSR-ordered msgbuf. Vectorized: lane (r8,c8) loads
// bf16x8 (16 B); 8 rows per step; shfl_xor(8/16/32) column reduce.
__global__ __launch_bounds__(256, 4) void gather_kernel(
    const int* __restrict__ rowptrA, const int* __restrict__ rowptrB,
    const unsigned short* __restrict__ msgbufA, const unsigned short* __restrict__ msgbufB,
    float* __restrict__ aggrA, float* __restrict__ aggrB)
{
    const int tid = threadIdx.x;
    const int wave = tid >> 6, lane = tid & 63;
    const int r8 = lane >> 3, c8 = lane & 7;
    const int nwaves = gridDim.x * 4;
    for (int u = blockIdx.x * 4 + wave; u < 16384; u += nwaves) {
        const int br = u >> 13;
        const int n = u & 8191;
        const int* rowptr = br ? rowptrB : rowptrA;
        const unsigned short* mb = br ? msgbufB : msgbufA;
        float* aggr = br ? aggrB : aggrA;
        int base = rowptr[n];
        int deg = rowptr[n + 1] - base;
        float a[8];
        #pragma unroll
        for (int j = 0; j < 8; j++) a[j] = 0.f;
        int i = 0;
        for (; i + 8 <= deg; i += 8) {
            bf16x8 v = *(const bf16x8*)(mb + (size_t)(base + i + r8) * 64 + c8 * 8);
            #pragma unroll
            for (int j = 0; j < 8; j++) a[j] += bf2f((unsigned short)v[j]);
        }
        int rem = deg - i;
        if (r8 < rem) {
            bf16x8 v = *(const bf16x8*)(mb + (size_t)(base + i + r8) * 64 + c8 * 8);
            #pragma unroll
            for (int j = 0; j < 8; j++) a[j] += bf2f((unsigned short)v[j]);
        }
        #pragma unroll
        for (int j = 0; j < 8; j++) {
            a[j] += __shfl_xor(a[j], 8);
            a[j] += __shfl_xor(a[j], 16);
            a[j] += __shfl_xor(a[j], 32);
        }
        if (r8 == 0) {
            float inv = 1.0f / fmaxf((float)deg, 1.0f);
            float4 w0 = make_float4(a[0] * inv, a[1] * inv, a[2] * inv, a[3] * inv);
            float4 w1 = make_float4(a[4] * inv, a[5] * inv, a[6] * inv, a[7] * inv);
            *(float4*)(aggr + (size_t)n * 64 + c8 * 8) = w0;
            *(float4*)(aggr + (size_t)n * 64 + c8 * 8 + 4) = w1;
        }
    }
}

// ---------------------------------------------------------------------------
__global__ __launch_bounds__(256, 2) void qkv_kernel(
    const unsigned short* __restrict__ hbA, const unsigned short* __restrict__ hbB,
    const float* __restrict__ qW, const float* __restrict__ kW,
    const float* __restrict__ vW,
    unsigned short* __restrict__ qo, unsigned short* __restrict__ ko,
    unsigned short* __restrict__ vTo)
{
    __shared__ __attribute__((aligned(16))) short Wq[64 * 72];
    __shared__ __attribute__((aligned(16))) short Wk[64 * 72];
    __shared__ __attribute__((aligned(16))) short Wv[64 * 72];
    const int tid = threadIdx.x;
    for (int i = tid; i < 4096; i += 256) {
        int n = i >> 6, kk = i & 63;
        Wq[n * 72 + kk] = (short)f2bf(qW[kk * 64 + n]);
        Wk[n * 72 + kk] = (short)f2bf(kW[kk * 64 + n]);
        Wv[n * 72 + kk] = (short)f2bf(vW[kk * 64 + n]);
    }
    __syncthreads();
    const int wave = tid >> 6, lane = tid & 63, l15 = lane & 15, g = lane >> 4;
    const int row0 = blockIdx.x * 64 + wave * 16;
    bf16x8 aA[2], aB[2];
    aA[0] = *(const bf16x8*)(hbA + (size_t)(row0 + l15) * 64 + 8 * g);
    aA[1] = *(const bf16x8*)(hbA + (size_t)(row0 + l15) * 64 + 32 + 8 * g);
    aB[0] = *(const bf16x8*)(hbB + (size_t)(row0 + l15) * 64 + 8 * g);
    aB[1] = *(const bf16x8*)(hbB + (size_t)(row0 + l15) * 64 + 32 + 8 * g);
    floatx4 aq[4], ak4[4], av[4];
    #pragma unroll
    for (int t = 0; t < 4; t++) { aq[t] = (floatx4)0.0f; ak4[t] = (floatx4)0.0f; av[t] = (floatx4)0.0f; }
    #pragma unroll
    for (int c = 0; c < 2; c++) {
        #pragma unroll
        for (int t = 0; t < 4; t++) {
            int wo = (t * 16 + l15) * 72 + 32 * c + 8 * g;
            aq[t] = MFMA16(aA[c], *(const bf16x8*)(&Wq[wo]), aq[t]);
            ak4[t] = MFMA16(aB[c], *(const bf16x8*)(&Wk[wo]), ak4[t]);
            av[t] = MFMA16(aB[c], *(const bf16x8*)(&Wv[wo]), av[t]);
        }
    }
    #pragma unroll
    for (int t = 0; t < 4; t++) {
        #pragma unroll
        for (int r = 0; r < 4; r++) {
            int orow = row0 + 4 * g + r, ocol = t * 16 + l15;
            qo[(size_t)orow * 64 + ocol] = f2bf(lrelu(aq[t][r]));
            ko[(size_t)orow * 64 + ocol] = f2bf(lrelu(ak4[t][r]));
            vTo[(size_t)ocol * 8192 + orow] = f2bf(av[t][r]);   // v transposed
        }
    }
}

// ---------------------------------------------------------------------------
// Flash attention, K-split=8, direct L2 b-frag loads, no barriers.
__global__ __launch_bounds__(256, 4) void attn_kernel(
    const unsigned short* __restrict__ qb_, const unsigned short* __restrict__ kb_,
    const unsigned short* __restrict__ vT,
    float* __restrict__ Opart, float* __restrict__ ml)
{
    __shared__ __attribute__((aligned(16))) short pbuf[4][16 * 72];
    const int tid = threadIdx.x;
    const int wave = tid >> 6, lane = tid & 63, l15 = lane & 15, g = lane >> 4;
    const int qblock = blockIdx.x >> 3;         // 128 q-blocks
    const int split = blockIdx.x & 7;           // 8 k-splits
    const int qrow0 = qblock * 64 + wave * 16;
    const int kbase = split * 1024;
    bf16x8 qf[2];
    qf[0] = *(const bf16x8*)(qb_ + (size_t)(qrow0 + l15) * 64 + 8 * g);
    qf[1] = *(const bf16x8*)(qb_ + (size_t)(qrow0 + l15) * 64 + 32 + 8 * g);
    float m_[4], l_[4];
    floatx4 oacc[4];
    #pragma unroll
    for (int r = 0; r < 4; r++) { m_[r] = -1.0e30f; l_[r] = 0.f; }
    #pragma unroll
    for (int t = 0; t < 4; t++) oacc[t] = (floatx4)0.0f;

    for (int kt = 0; kt < 16; kt++) {
        const int krow0 = kbase + kt * 64;
        floatx4 sacc[4];
        #pragma unroll
        for (int t = 0; t < 4; t++) sacc[t] = (floatx4)0.0f;
        #pragma unroll
        for (int c = 0; c < 2; c++) {
            #pragma unroll
            for (int t = 0; t < 4; t++) {
                bf16x8 b = *(const bf16x8*)(kb_ + (size_t)(krow0 + t * 16 + l15) * 64 + 32 * c + 8 * g);
                sacc[t] = MFMA16(qf[c], b, sacc[t]);
            }
        }
        #pragma unroll
        for (int r = 0; r < 4; r++) {
            float mx = fmaxf(fmaxf(sacc[0][r], sacc[1][r]), fmaxf(sacc[2][r], sacc[3][r]));
            mx = rowmax16(mx);
            float mn = fmaxf(m_[r], mx);
            float sc = __expf(fminf(m_[r] - mn, 0.f));
            float ps = 0.f;
            int rowoff = (4 * g + r) * 72;
            #pragma unroll
            for (int t = 0; t < 4; t++) {
                float p = __expf(fminf(sacc[t][r] - mn, 0.f));
                ps += p;
                pbuf[wave][rowoff + t * 16 + l15] = (short)f2bf(p);
            }
            ps = rowsum16(ps);
            l_[r] = l_[r] * sc + ps;
            m_[r] = mn;
            #pragma unroll
            for (int t = 0; t < 4; t++) oacc[t][r] *= sc;
        }
        bf16x8 pf[2];
        pf[0] = *(const bf16x8*)(&pbuf[wave][l15 * 72 + 8 * g]);
        pf[1] = *(const bf16x8*)(&pbuf[wave][l15 * 72 + 32 + 8 * g]);
        #pragma unroll
        for (int c = 0; c < 2; c++) {
            #pragma unroll
            for (int t = 0; t < 4; t++) {
                bf16x8 b = *(const bf16x8*)(vT + (size_t)(t * 16 + l15) * 8192 + krow0 + 32 * c + 8 * g);
                oacc[t] = MFMA16(pf[c], b, oacc[t]);
            }
        }
    }
    #pragma unroll
    for (int t = 0; t < 4; t++) {
        #pragma unroll
        for (int r = 0; r < 4; r++) {
            int row = qrow0 + 4 * g + r;
            Opart[((size_t)split * 8192 + row) * 64 + t * 16 + l15] = oacc[t][r];
        }
    }
    if (l15 == 0) {
        #pragma unroll
        for (int r = 0; r < 4; r++) {
            int row = qrow0 + 4 * g + r;
            ml[((size_t)split * 8192 + row) * 2 + 0] = m_[r];
            ml[((size_t)split * 8192 + row) * 2 + 1] = l_[r];
        }
    }
}

__global__ void combine_kernel(const float* __restrict__ Opart, const float* __restrict__ ml,
                               unsigned short* __restrict__ attb)
{
    int idx = blockIdx.x * 256 + threadIdx.x;   // 8192*64
    int row = idx >> 6, col = idx & 63;
    float mm = -1.0e30f;
    #pragma unroll
    for (int s = 0; s < 8; s++) mm = fmaxf(mm, ml[((size_t)s * 8192 + row) * 2]);
    float l = 0.f, o = 0.f;
    #pragma unroll
    for (int s = 0; s < 8; s++) {
        float w = __expf(ml[((size_t)s * 8192 + row) * 2] - mm);
        l += w * ml[((size_t)s * 8192 + row) * 2 + 1];
        o += w * Opart[((size_t)s * 8192 + row) * 64 + col];
    }
    attb[(size_t)row * 64 + col] = f2bf(o / l);
}

// ---------------------------------------------------------------------------
__global__ __launch_bounds__(256, 2) void node_kernel(
    const float* __restrict__ hA, const float* __restrict__ hB,
    const float* __restrict__ origA, const float* __restrict__ origB,
    const unsigned short* __restrict__ attb,
    const float* __restrict__ aggrA, const float* __restrict__ aggrB,
    const float* __restrict__ nW1, const float* __restrict__ nb1,
    const float* __restrict__ ng1, const float* __restrict__ nbt1,
    const float* __restrict__ nW2, const float* __restrict__ nb2,
    const float* __restrict__ ng2, const float* __restrict__ nbt2,
    float* __restrict__ out)
{
    __shared__ __attribute__((aligned(16))) short W1t[64 * 264];
    __shared__ __attribute__((aligned(16))) short W2t[64 * 72];
    __shared__ __attribute__((aligned(16))) float pb[6 * 64];
    __shared__ __attribute__((aligned(16))) short ubuf[4][16 * 72];
    const int tid = threadIdx.x;
    for (int i = tid; i < 64 * 256; i += 256) {
        int n = i >> 8, kk = i & 255;
        W1t[n * 264 + kk] = (short)f2bf(nW1[kk * 64 + n]);
    }
    for (int i = tid; i < 4096; i += 256) {
        int n = i >> 6, kk = i & 63;
        W2t[n * 72 + kk] = (short)f2bf(nW2[kk * 64 + n]);
    }
    if (tid < 64) {
        pb[tid]       = nb1[tid];
        pb[64 + tid]  = ng1[tid];
        pb[128 + tid] = nbt1[tid];
        pb[192 + tid] = nb2[tid];
        pb[256 + tid] = ng2[tid];
        pb[320 + tid] = nbt2[tid];
    }
    __syncthreads();   // only barrier
    const int wave = tid >> 6, lane = tid & 63, l15 = lane & 15, g = lane >> 4;
    const int unit = blockIdx.x * 4 + wave;          // 1024 units
    const int br = unit >> 9;
    const int nb_ = (unit & 511) * 16;
    const float* h = br ? hB : hA;
    const float* orig = br ? origB : origA;
    const float* aggr = br ? aggrB : aggrA;
    const size_t outbase = br ? 573440 : 24576;

    const int row = nb_ + l15;

    bf16x8 af[8];
    af[0] = cvt8(h + (size_t)row * 64 + 8 * g);
    af[1] = cvt8(h + (size_t)row * 64 + 32 + 8 * g);
    af[2] = cvt8(aggr + (size_t)row * 64 + 8 * g);
    af[3] = cvt8(aggr + (size_t)row * 64 + 32 + 8 * g);
    if (br == 0) {
        af[4] = *(const bf16x8*)(attb + (size_t)row * 64 + 8 * g);
        af[5] = *(const bf16x8*)(attb + (size_t)row * 64 + 32 + 8 * g);
    } else {
        af[4] = (bf16x8)0;
        af[5] = (bf16x8)0;
    }
    af[6] = cvt8(orig + (size_t)row * 64 + 8 * g);
    af[7] = cvt8(orig + (size_t)row * 64 + 32 + 8 * g);

    floatx4 acc1[4];
    #pragma unroll
    for (int t = 0; t < 4; t++) acc1[t] = (floatx4)0.0f;
    #pragma unroll
    for (int c = 0; c < 8; c++) {
        #pragma unroll
        for (int t = 0; t < 4; t++) {
            bf16x8 b = *(const bf16x8*)(&W1t[(t * 16 + l15) * 264 + 32 * c + 8 * g]);
            acc1[t] = MFMA16(af[c], b, acc1[t]);
        }
    }
    float vv[4][4];
    #pragma unroll
    for (int t = 0; t < 4; t++)
        #pragma unroll
        for (int r = 0; r < 4; r++) vv[t][r] = acc1[t][r] + pb[t * 16 + l15];
    #pragma unroll
    for (int r = 0; r < 4; r++) {
        float s1 = vv[0][r] + vv[1][r] + vv[2][r] + vv[3][r];
        float s2 = vv[0][r] * vv[0][r] + vv[1][r] * vv[1][r] + vv[2][r] * vv[2][r] + vv[3][r] * vv[3][r];
        s1 = rowsum16(s1);
        s2 = rowsum16(s2);
        float mean = s1 * 0.015625f;
        float rstd = ln_rstd(s2, mean);
        int rowoff = (4 * g + r) * 72;
        #pragma unroll
        for (int t = 0; t < 4; t++) {
            int colx = t * 16 + l15;
            float x = (vv[t][r] - mean) * rstd * pb[64 + colx] + pb[128 + colx];
            x = lrelu(x);
            ubuf[wave][rowoff + colx] = (short)f2bf(x);
        }
    }
    bf16x8 a2[2];
    a2[0] = *(const bf16x8*)(&ubuf[wave][l15 * 72 + 8 * g]);
    a2[1] = *(const bf16x8*)(&ubuf[wave][l15 * 72 + 32 + 8 * g]);
    floatx4 acc2[4];
    #pragma unroll
    for (int t = 0; t < 4; t++) acc2[t] = (floatx4)0.0f;
    #pragma unroll
    for (int c = 0; c < 2; c++) {
        #pragma unroll
        for (int t = 0; t < 4; t++) {
            bf16x8 b = *(const bf16x8*)(&W2t[(t * 16 + l15) * 72 + 32 * c + 8 * g]);
            acc2[t] = MFMA16(a2[c], b, acc2[t]);
        }
    }
    float u2[4][4];
    #pragma unroll
    for (int t = 0; t < 4; t++)
        #pragma unroll
        for (int r = 0; r < 4; r++) u2[t][r] = acc2[t][r] + pb[192 + t * 16 + l15];
    #pragma unroll
    for (int r = 0; r < 4; r++) {
        float s1 = u2[0][r] + u2[1][r] + u2[2][r] + u2[3][r];
        float s2 = u2[0][r] * u2[0][r] + u2[1][r] * u2[1][r] + u2[2][r] * u2[2][r] + u2[3][r] * u2[3][r];
        s1 = rowsum16(s1);
        s2 = rowsum16(s2);
        float mean = s1 * 0.015625f;
        float rstd = ln_rstd(s2, mean);
        #pragma unroll
        for (int t = 0; t < 4; t++) {
            int colx = t * 16 + l15;
            float u = (u2[t][r] - mean) * rstd * pb[256 + colx] + pb[320 + colx];
            size_t orow = (size_t)(nb_ + 4 * g + r);
            float hh = h[orow * 64 + colx];
            out[outbase + orow * 64 + colx] = 0.5f * u + 0.5f * hh;
        }
    }
}

// ---------------------------------------------------------------------------
__global__ void xnew_kernel(
    const float* __restrict__ coordsA, const float* __restrict__ origcA,
    const float* __restrict__ coordsB, const float* __restrict__ origcB,
    const float* __restrict__ xupA, const float* __restrict__ xupB,
    const int* __restrict__ rowptrA, const int* __restrict__ rowptrB,
    float* __restrict__ out)
{
    int i = blockIdx.x * 256 + threadIdx.x;   // 49152 total
    int br = (i >= 24576) ? 1 : 0;
    int j = i - br * 24576;
    const float* coords = br ? coordsB : coordsA;
    const float* origc = br ? origcB : origcA;
    const float* xup = br ? xupB : xupA;
    const int* rp = br ? rowptrB : rowptrA;
    int node = j / 3;
    float cnt = (float)(rp[node + 1] - rp[node]);
    float val = 0.25f * origc[j] + 0.75f * coords[j] + xup[j] / fmaxf(cnt, 1.0f);
    out[(br ? 548864 : 0) + j] = val;
}

// ---------------------------------------------------------------------------
extern "C" void kernel_launch(void* const* d_in, const int* in_sizes, int n_in,
                              void* d_out, int out_size, void* d_ws, size_t ws_size,
                              hipStream_t stream)
{
    int base = n_in - 29;
    for (int i = 0; i < n_in; i++) {
        if (in_sizes[i] == 11200) { base = i; break; }
    }
    const float* coordsA = (const float*)d_in[0];
    const float* hA      = (const float*)d_in[1];
    const float* origA   = (const float*)d_in[2];
    const float* origcA  = (const float*)d_in[3];
    const float* efA     = (const float*)d_in[4];
    const float* coordsB = (const float*)d_in[5];
    const float* hB      = (const float*)d_in[6];
    const float* origB   = (const float*)d_in[7];
    const float* origcB  = (const float*)d_in[8];
    const float* efB     = (const float*)d_in[9];
    const float* P[25];
    for (int k = 0; k < 25; k++) P[k] = (const float*)d_in[base + k];
    const int* srcA = (const int*)d_in[base + 25];
    const int* dstA = (const int*)d_in[base + 26];
    const int* srcB = (const int*)d_in[base + 27];
    const int* dstB = (const int*)d_in[base + 28];

    char* ws = (char*)d_ws;
    unsigned short* msgbufA = (unsigned short*)(ws + 0);          // 33.5 MB
    unsigned short* msgbufB = (unsigned short*)(ws + 33554432);   // 33.5 MB
    float* Opart  = (float*)(ws + 0);                             // 16 MB (reuse after gather)
    float* mlbuf  = (float*)(ws + 16777216);                      // 512 KB (reuse)
    unsigned short* hbA  = (unsigned short*)(ws + 67108864);      // 1 MB
    unsigned short* hbB  = (unsigned short*)(ws + 68157440);
    unsigned short* efbA = (unsigned short*)(ws + 69206016);      // 16 MB
    unsigned short* efbB = (unsigned short*)(ws + 85983232);
    float* aggrA  = (float*)(ws + 102760448);                     // 2 MB
    float* aggrB  = (float*)(ws + 104857600);
    unsigned short* qbuf = (unsigned short*)(ws + 106954752);     // 1 MB
    unsigned short* kbuf = (unsigned short*)(ws + 108003328);
    unsigned short* vTb  = (unsigned short*)(ws + 109051904);
    unsigned short* attb = (unsigned short*)(ws + 110100480);
    // zero region (one memset, 327,680 B): xupA,xupB,histA,histB,curA,curB
    float* xupA = (float*)(ws + 111149056);
    float* xupB = (float*)(ws + 111247360);
    int* histA  = (int*)(ws + 111345664);
    int* histB  = (int*)(ws + 111378432);
    int* curA   = (int*)(ws + 111411200);
    int* curB   = (int*)(ws + 111443968);
    int* rowptrA = (int*)(ws + 111476736);
    int* rowptrB = (int*)(ws + 111517696);
    int* posA   = (int*)(ws + 111558656);                          // 1 MB
    int* posB   = (int*)(ws + 112607232);                          // 1 MB
    float* xrbA = (float*)(ws + 117440512);                        // 3 MB
    float* xrbB = (float*)(ws + 120586240);                        // 3 MB
    unsigned short* rbfbA = (unsigned short*)(ws + 123731968);     // 8 MB
    unsigned short* rbfbB = (unsigned short*)(ws + 132120576);     // 8 MB
    float* out = (float*)d_out;

    hipMemsetAsync(ws + 111149056, 0, 327680, stream);

    prep_kernel<<<17408, 256, 0, stream>>>(hA, hB, efA, efB, hbA, hbB, efbA, efbB);

    edgeprep_kernel<<<2048, 256, 0, stream>>>(coordsA, srcA, dstA,
                                              coordsB, srcB, dstB,
                                              xrbA, xrbB, rbfbA, rbfbB);

    hist_kernel<<<1024, 256, 0, stream>>>(dstA, dstB, histA, histB);
    scan_kernel<<<2, 1024, 0, stream>>>(histA, histB, rowptrA, rowptrB);
    scatter_kernel<<<1024, 256, 0, stream>>>(dstA, dstB, rowptrA, rowptrB,
                                             curA, curB, posA, posB);

    edge_kernel<<<1024, 512, 0, stream>>>(
        hbA, efbA, srcA, dstA, posA, xrbA, rbfbA,
        hbB, efbB, srcB, dstB, posB, xrbB, rbfbB,
        P[0], P[1], P[2], P[3], P[4], P[5], P[6], P[7],
        P[19], P[20], P[21], P[22], P[23], P[24],
        msgbufA, msgbufB, xupA, xupB);

    gather_kernel<<<2048, 256, 0, stream>>>(rowptrA, rowptrB, msgbufA, msgbufB,
                                            aggrA, aggrB);

    qkv_kernel<<<128, 256, 0, stream>>>(hbA, hbB, P[8], P[9], P[10], qbuf, kbuf, vTb);

    attn_kernel<<<1024, 256, 0, stream>>>(qbuf, kbuf, vTb, Opart, mlbuf);
    combine_kernel<<<2048, 256, 0, stream>>>(Opart, mlbuf, attb);

    node_kernel<<<256, 256, 0, stream>>>(
        hA, hB, origA, origB, attb, aggrA, aggrB,
        P[11], P[12], P[13], P[14], P[15], P[16], P[17], P[18], out);

    xnew_kernel<<<192, 256, 0, stream>>>(
        coordsA, origcA, coordsB, origcB, xupA, xupB, rowptrA, rowptrB, out);
}

// Round 13
// 345.014 us; speedup vs baseline: 1.0071x; 1.0071x over previous
//
#include <hip/hip_runtime.h>
#include <cstdint>
#include <cstddef>

// ---------------------------------------------------------------------------
// Fine_Grain_Layer. f32 I/O, bf16 MFMA operands, f32 accumulate.
// R20 -> R21: LOCK THE CHAMPION. R19 (flattened skew) and R20 (setprio) were
// both within noise of R18 but never better (345.1 / 345.8 / 347.5); restore
// R18 exactly (k-loop 2-group interleave, no setprio).
// Measurement note: per-dispatch rocprof durs vary +/-15% across replays
// (R18 edge <151, R19 edge 174, totals equal) -- totals are ground truth.
// Ledger (12 rounds): work-removal grafts won (DPP reductions, VGPR biases,
// rbf/xr precompute, 2-group batched loads: 393 -> 345); all structural
// reshuffles / pipelines / scheduling hints were neutral-to-negative.
// Breakdown: ~155us harness poison fill (fixed) + edge ~165+-12
// (serial-chain latency-bound, characterized) + ~25us remainder.
// ---------------------------------------------------------------------------

typedef short bf16x8 __attribute__((ext_vector_type(8)));
typedef float floatx4 __attribute__((ext_vector_type(4)));

#define MFMA16(a, b, c) __builtin_amdgcn_mfma_f32_16x16x32_bf16((a), (b), (c), 0, 0, 0)

// DPP lane-move within 16-lane rows (VALU pipe, no LDS). ctrl must be literal.
#define DPPMV(x, ctrl) __builtin_bit_cast(float, __builtin_amdgcn_update_dpp( \
        0, __builtin_bit_cast(int, (x)), (ctrl), 0xF, 0xF, true))

__device__ __forceinline__ unsigned short f2bf(float f) {
    unsigned int u = __builtin_bit_cast(unsigned int, f);
    u += 0x7fffu + ((u >> 16) & 1u);   // round to nearest even
    return (unsigned short)(u >> 16);
}
__device__ __forceinline__ float bf2f(unsigned short u) {
    unsigned int x = ((unsigned int)u) << 16;
    return __builtin_bit_cast(float, x);
}
__device__ __forceinline__ bf16x8 cvt8(const float* __restrict__ p) {
    float4 v0 = *(const float4*)(p);
    float4 v1 = *(const float4*)(p + 4);
    bf16x8 r;
    r[0] = (short)f2bf(v0.x); r[1] = (short)f2bf(v0.y);
    r[2] = (short)f2bf(v0.z); r[3] = (short)f2bf(v0.w);
    r[4] = (short)f2bf(v1.x); r[5] = (short)f2bf(v1.y);
    r[6] = (short)f2bf(v1.z); r[7] = (short)f2bf(v1.w);
    return r;
}
// sum/max over each 16-lane group: quads, then cross-quad, then cross-8.
__device__ __forceinline__ float rowsum16(float x) {
    x += DPPMV(x, 0xB1);    // quad_perm [1,0,3,2]  (xor 1)
    x += DPPMV(x, 0x4E);    // quad_perm [2,3,0,1]  (xor 2)
    x += DPPMV(x, 0x141);   // row_half_mirror      (other quad in 8)
    x += DPPMV(x, 0x140);   // row_mirror           (other 8 in 16)
    return x;
}
__device__ __forceinline__ float rowmax16(float x) {
    x = fmaxf(x, DPPMV(x, 0xB1));
    x = fmaxf(x, DPPMV(x, 0x4E));
    x = fmaxf(x, DPPMV(x, 0x141));
    x = fmaxf(x, DPPMV(x, 0x140));
    return x;
}
__device__ __forceinline__ float lrelu(float x) { return x > 0.f ? x : 0.01f * x; }
__device__ __forceinline__ float ln_rstd(float s2, float mean) {
    float var = s2 * 0.015625f - mean * mean;
    return rsqrtf(fmaxf(var, 0.0f) + 1e-5f);
}

__constant__ float INVSIG[16] = {
    1.0f, 0.6666666865f, 0.4444444597f, 0.2962962985f, 0.1975308657f,
    0.1316872428f, 0.0877914950f, 0.0585276633f, 0.0390184447f, 0.0260122959f,
    0.0173415299f, 0.0115610203f, 0.0077073467f, 0.0051382311f, 0.0034254875f, 0.0f};

// ---------------------------------------------------------------------------
// Pre-convert h (2x524288) and ef (2x8388608) to bf16. Quad-granular.
__global__ void prep_kernel(const float* __restrict__ hA, const float* __restrict__ hB,
                            const float* __restrict__ efA, const float* __restrict__ efB,
                            unsigned short* __restrict__ hbA, unsigned short* __restrict__ hbB,
                            unsigned short* __restrict__ efbA, unsigned short* __restrict__ efbB)
{
    int q = blockIdx.x * 256 + threadIdx.x;   // 4,456,448 quads exactly
    const float* s; unsigned short* d; int off;
    if (q < 131072)        { s = hA;  d = hbA;  off = q; }
    else if (q < 262144)   { s = hB;  d = hbB;  off = q - 131072; }
    else if (q < 2359296)  { s = efA; d = efbA; off = q - 262144; }
    else                   { s = efB; d = efbB; off = q - 2359296; }
    float4 v = *(const float4*)(s + (size_t)off * 4);
    ushort4 o;
    o.x = f2bf(v.x); o.y = f2bf(v.y); o.z = f2bf(v.z); o.w = f2bf(v.w);
    *(ushort4*)(d + (size_t)off * 4) = o;
}

// ---------------------------------------------------------------------------
// Per-edge precompute: xr[e] (3 f32) and rbf row (16 bf16). Streaming.
__global__ void edgeprep_kernel(const float* __restrict__ coordsA, const int* __restrict__ srcA,
                                const int* __restrict__ dstA,
                                const float* __restrict__ coordsB, const int* __restrict__ srcB,
                                const int* __restrict__ dstB,
                                float* __restrict__ xrbA, float* __restrict__ xrbB,
                                unsigned short* __restrict__ rbfbA, unsigned short* __restrict__ rbfbB)
{
    int i = blockIdx.x * 256 + threadIdx.x;   // 524288 exactly
    int brB = i >= 262144;
    int e = i - (brB ? 262144 : 0);
    const float* coords = brB ? coordsB : coordsA;
    const int* src = brB ? srcB : srcA;
    const int* dst = brB ? dstB : dstA;
    float* xrb = brB ? xrbB : xrbA;
    unsigned short* rbfb = brB ? rbfbB : rbfbA;

    int s = src[e], d0 = dst[e];
    float xr0 = coords[s * 3 + 0] - coords[d0 * 3 + 0];
    float xr1 = coords[s * 3 + 1] - coords[d0 * 3 + 1];
    float xr2 = coords[s * 3 + 2] - coords[d0 * 3 + 2];
    float d2 = xr0 * xr0 + xr1 * xr1 + xr2 * xr2;
    xrb[(size_t)e * 3 + 0] = xr0;
    xrb[(size_t)e * 3 + 1] = xr1;
    xrb[(size_t)e * 3 + 2] = xr2;
    ushort4 o0, o1, o2, o3;
    unsigned short rv[16];
    #pragma unroll
    for (int j = 0; j < 15; j++) rv[j] = f2bf(__expf(-d2 * INVSIG[j]));
    rv[15] = 0;
    o0.x = rv[0];  o0.y = rv[1];  o0.z = rv[2];  o0.w = rv[3];
    o1.x = rv[4];  o1.y = rv[5];  o1.z = rv[6];  o1.w = rv[7];
    o2.x = rv[8];  o2.y = rv[9];  o2.z = rv[10]; o2.w = rv[11];
    o3.x = rv[12]; o3.y = rv[13]; o3.z = rv[14]; o3.w = rv[15];
    *(ushort4*)(rbfb + (size_t)e * 16)      = o0;
    *(ushort4*)(rbfb + (size_t)e * 16 + 4)  = o1;
    *(ushort4*)(rbfb + (size_t)e * 16 + 8)  = o2;
    *(ushort4*)(rbfb + (size_t)e * 16 + 12) = o3;
}

// ---------------------------------------------------------------------------
__global__ void hist_kernel(const int* __restrict__ dstA, const int* __restrict__ dstB,
                            int* __restrict__ histA, int* __restrict__ histB)
{
    int e = blockIdx.x * 256 + threadIdx.x;   // exactly 262144
    atomicAdd(&histA[dstA[e]], 1);
    atomicAdd(&histB[dstB[e]], 1);
}

__global__ void scan_kernel(const int* __restrict__ histA, const int* __restrict__ histB,
                            int* __restrict__ rowptrA, int* __restrict__ rowptrB)
{
    const int b = blockIdx.x;   // 0 = A, 1 = B
    const int* hist = b ? histB : histA;
    int* rowptr = b ? rowptrB : rowptrA;
    __shared__ int part[1024];
    int t = threadIdx.x;
    int v[8]; int s = 0;
    #pragma unroll
    for (int j = 0; j < 8; j++) { v[j] = hist[t * 8 + j]; s += v[j]; }
    part[t] = s;
    __syncthreads();
    for (int off = 1; off < 1024; off <<= 1) {
        int x = part[t];
        int y = (t >= off) ? part[t - off] : 0;
        __syncthreads();
        part[t] = x + y;
        __syncthreads();
    }
    int run = (t > 0) ? part[t - 1] : 0;
    #pragma unroll
    for (int j = 0; j < 8; j++) { rowptr[t * 8 + j] = run; run += v[j]; }
    if (t == 1023) rowptr[8192] = run;
}

// pos[e] = slot of edge e in dst-CSR order
__global__ void scatter_kernel(const int* __restrict__ dstA, const int* __restrict__ dstB,
                               const int* __restrict__ rowptrA, const int* __restrict__ rowptrB,
                               int* __restrict__ curA, int* __restrict__ curB,
                               int* __restrict__ posA, int* __restrict__ posB)
{
    int e = blockIdx.x * 256 + threadIdx.x;   // exactly 262144
    int dA = dstA[e];
    posA[e] = rowptrA[dA] + atomicAdd(&curA[dA], 1);
    int dB = dstB[e];
    posB[e] = rowptrB[dB] + atomicAdd(&curB[dB], 1);
}

// ---------------------------------------------------------------------------
// FRONT: gathers + layer1 MFMA + LN1 -> XOUT[4][4] (registers only).
// Braced block = fresh scoped locals per expansion (no captures).
#define EDGE_FRONT(EIDX, SV, DV, XOUT)                                          \
    {                                                                           \
        bf16x8 f0 = *(const bf16x8*)(hb + (size_t)(SV) * 64 + 8 * g);           \
        bf16x8 f1 = *(const bf16x8*)(hb + (size_t)(SV) * 64 + 32 + 8 * g);      \
        bf16x8 f2 = *(const bf16x8*)(hb + (size_t)(DV) * 64 + 8 * g);           \
        bf16x8 f3 = *(const bf16x8*)(hb + (size_t)(DV) * 64 + 32 + 8 * g);      \
        bf16x8 f4 = *(const bf16x8*)(efb + (size_t)(EIDX) * 32 + 8 * g);        \
        bf16x8 f5 = (g < 2) ? *(const bf16x8*)(rbfb + (size_t)(EIDX) * 16 + 8 * g) : (bf16x8)0; \
        floatx4 acc[4];                                                         \
        _Pragma("unroll") for (int t = 0; t < 4; t++) acc[t] = (floatx4)0.0f;   \
        _Pragma("unroll") for (int t = 0; t < 4; t++) {                         \
            const short* wr = &Wt1[(t * 16 + l15) * 200 + 8 * g];               \
            acc[t] = MFMA16(f0, *(const bf16x8*)(wr),       acc[t]);            \
            acc[t] = MFMA16(f1, *(const bf16x8*)(wr + 32),  acc[t]);            \
            acc[t] = MFMA16(f2, *(const bf16x8*)(wr + 64),  acc[t]);            \
            acc[t] = MFMA16(f3, *(const bf16x8*)(wr + 96),  acc[t]);            \
            acc[t] = MFMA16(f4, *(const bf16x8*)(wr + 128), acc[t]);            \
            acc[t] = MFMA16(f5, *(const bf16x8*)(wr + 160), acc[t]);            \
        }                                                                       \
        float vv[4][4];                                                         \
        _Pragma("unroll") for (int t = 0; t < 4; t++)                           \
            _Pragma("unroll") for (int r = 0; r < 4; r++) vv[t][r] = acc[t][r] + b1v[t]; \
        _Pragma("unroll") for (int r = 0; r < 4; r++) {                         \
            float s1 = vv[0][r] + vv[1][r] + vv[2][r] + vv[3][r];               \
            float s2 = vv[0][r] * vv[0][r] + vv[1][r] * vv[1][r] + vv[2][r] * vv[2][r] + vv[3][r] * vv[3][r]; \
            s1 = rowsum16(s1);                                                  \
            s2 = rowsum16(s2);                                                  \
            float mean = s1 * 0.015625f;                                        \
            float rstd = ln_rstd(s2, mean);                                     \
            _Pragma("unroll") for (int t = 0; t < 4; t++)                       \
                XOUT[t][r] = lrelu((vv[t][r] - mean) * rstd * g1v[t] + t1v[t]); \
        }                                                                       \
    }

// BACK: msgb round trips + layer2 + LN2 + CSR store + coef MLP + atomic.
#define EDGE_BACK(XIN, SLOTV, DV, XRGV)                                         \
    {                                                                           \
        _Pragma("unroll") for (int r = 0; r < 4; r++) {                         \
            int rowoff = (4 * g + r) * 72;                                      \
            _Pragma("unroll") for (int t = 0; t < 4; t++)                       \
                msgb[wave][rowoff + t * 16 + l15] = (short)f2bf(XIN[t][r]);     \
        }                                                                       \
        bf16x8 a20 = *(const bf16x8*)(&msgb[wave][l15 * 72 + 8 * g]);           \
        bf16x8 a21 = *(const bf16x8*)(&msgb[wave][l15 * 72 + 32 + 8 * g]);      \
        floatx4 acc2[4];                                                        \
        _Pragma("unroll") for (int t = 0; t < 4; t++) acc2[t] = (floatx4)0.0f;  \
        _Pragma("unroll") for (int t = 0; t < 4; t++) {                         \
            const short* wr2 = &Wt2s[(t * 16 + l15) * 72 + 8 * g];              \
            acc2[t] = MFMA16(a20, *(const bf16x8*)(wr2),      acc2[t]);         \
            acc2[t] = MFMA16(a21, *(const bf16x8*)(wr2 + 32), acc2[t]);         \
        }                                                                       \
        float vm[4][4];                                                         \
        _Pragma("unroll") for (int t = 0; t < 4; t++)                           \
            _Pragma("unroll") for (int r = 0; r < 4; r++) vm[t][r] = acc2[t][r] + b2v[t]; \
        _Pragma("unroll") for (int r = 0; r < 4; r++) {                         \
            float s1 = vm[0][r] + vm[1][r] + vm[2][r] + vm[3][r];               \
            float s2 = vm[0][r] * vm[0][r] + vm[1][r] * vm[1][r] + vm[2][r] * vm[2][r] + vm[3][r] * vm[3][r]; \
            s1 = rowsum16(s1);                                                  \
            s2 = rowsum16(s2);                                                  \
            float mean = s1 * 0.015625f;                                        \
            float rstd = ln_rstd(s2, mean);                                     \
            _Pragma("unroll") for (int t = 0; t < 4; t++)                       \
                vm[t][r] = (vm[t][r] - mean) * rstd * g2v[t] + t2v[t];          \
        }                                                                       \
        _Pragma("unroll") for (int r = 0; r < 4; r++) {                         \
            int rowoff = (4 * g + r) * 72;                                      \
            _Pragma("unroll") for (int t = 0; t < 4; t++)                       \
                msgb[wave][rowoff + t * 16 + l15] = (short)f2bf(vm[t][r]);      \
        }                                                                       \
        bf16x8 a30 = *(const bf16x8*)(&msgb[wave][l15 * 72 + 8 * g]);           \
        bf16x8 a31 = *(const bf16x8*)(&msgb[wave][l15 * 72 + 32 + 8 * g]);      \
        {                                                                       \
            unsigned short* mrow = msgbuf + (size_t)(SLOTV) * 64;               \
            *(bf16x8*)(mrow + 8 * g)      = a30;                                \
            *(bf16x8*)(mrow + 32 + 8 * g) = a31;                                \
        }                                                                       \
        floatx4 acc3[4];                                                        \
        _Pragma("unroll") for (int t = 0; t < 4; t++) acc3[t] = (floatx4)0.0f;  \
        _Pragma("unroll") for (int t = 0; t < 4; t++) {                         \
            const short* wr3 = &Wc1s[(t * 16 + l15) * 72 + 8 * g];              \
            acc3[t] = MFMA16(a30, *(const bf16x8*)(wr3),      acc3[t]);         \
            acc3[t] = MFMA16(a31, *(const bf16x8*)(wr3 + 32), acc3[t]);         \
        }                                                                       \
        float w3[4][4];                                                         \
        _Pragma("unroll") for (int t = 0; t < 4; t++)                           \
            _Pragma("unroll") for (int r = 0; r < 4; r++) w3[t][r] = acc3[t][r] + c1v[t]; \
        float coefr[4];                                                         \
        _Pragma("unroll") for (int r = 0; r < 4; r++) {                         \
            float s1 = w3[0][r] + w3[1][r] + w3[2][r] + w3[3][r];               \
            float s2 = w3[0][r] * w3[0][r] + w3[1][r] * w3[1][r] + w3[2][r] * w3[2][r] + w3[3][r] * w3[3][r]; \
            s1 = rowsum16(s1);                                                  \
            s2 = rowsum16(s2);                                                  \
            float mean = s1 * 0.015625f;                                        \
            float rstd = ln_rstd(s2, mean);                                     \
            float p = 0.f;                                                      \
            _Pragma("unroll") for (int t = 0; t < 4; t++) {                     \
                float x = (w3[t][r] - mean) * rstd * cg1v[t] + ct1v[t];         \
                x = lrelu(x);                                                   \
                p += x * w2v[t];                                                \
            }                                                                   \
            p = rowsum16(p);                                                    \
            coefr[r] = p + cb2s;                                                \
        }                                                                       \
        int srcl = (l15 >> 2) << 4;                                             \
        float v0 = __shfl(coefr[0], srcl);                                      \
        float v1 = __shfl(coefr[1], srcl);                                      \
        float v2 = __shfl(coefr[2], srcl);                                      \
        float v3 = __shfl(coefr[3], srcl);                                      \
        int rsel = l15 & 3;                                                     \
        float cf = (rsel == 0) ? v0 : (rsel == 1) ? v1 : (rsel == 2) ? v2 : v3; \
        if (g < 3) {                                                            \
            atomicAdd(&xup[(size_t)(DV) * 3 + g], (XRGV) * cf);                 \
        }                                                                       \
    }

// Edge kernel: 2 independent groups per wave per k-iteration (two serial
// chains per wave = the ILP that 1-block/CU occupancy cannot give).
__global__ __launch_bounds__(512, 2) void edge_kernel(
    const unsigned short* __restrict__ hbA,
    const unsigned short* __restrict__ efbA, const int* __restrict__ srcA,
    const int* __restrict__ dstA, const int* __restrict__ posA,
    const float* __restrict__ xrbA, const unsigned short* __restrict__ rbfbA,
    const unsigned short* __restrict__ hbB,
    const unsigned short* __restrict__ efbB, const int* __restrict__ srcB,
    const int* __restrict__ dstB, const int* __restrict__ posB,
    const float* __restrict__ xrbB, const unsigned short* __restrict__ rbfbB,
    const float* __restrict__ eW1, const float* __restrict__ eb1,
    const float* __restrict__ eg1, const float* __restrict__ ebt1,
    const float* __restrict__ eW2, const float* __restrict__ eb2,
    const float* __restrict__ eg2, const float* __restrict__ ebt2,
    const float* __restrict__ cW1, const float* __restrict__ cb1,
    const float* __restrict__ cg1, const float* __restrict__ cbt1,
    const float* __restrict__ cW2, const float* __restrict__ cb2,
    unsigned short* __restrict__ msgbufA, unsigned short* __restrict__ msgbufB,
    float* __restrict__ xupA, float* __restrict__ xupB)
{
    __shared__ __attribute__((aligned(16))) short Wt1[64 * 200];   // 25600 B
    __shared__ __attribute__((aligned(16))) short Wt2s[64 * 72];   //  9216 B
    __shared__ __attribute__((aligned(16))) short Wc1s[64 * 72];   //  9216 B
    __shared__ __attribute__((aligned(16))) short msgb[8][16 * 72];// 18432 B -> 62464 total

    const int tid = threadIdx.x;

    for (int i = tid; i < 64 * 192; i += 512) {
        int n = i / 192, kk = i - n * 192;
        Wt1[n * 200 + kk] = (kk < 175) ? (short)f2bf(eW1[kk * 64 + n]) : (short)0;
    }
    for (int i = tid; i < 4096; i += 512) {
        int n = i >> 6, kk = i & 63;
        Wt2s[n * 72 + kk] = (short)f2bf(eW2[kk * 64 + n]);
        Wc1s[n * 72 + kk] = (short)f2bf(cW1[kk * 64 + n]);
    }

    const int wave = tid >> 6;
    const int lane = tid & 63;
    const int l15 = lane & 15;
    const int g = lane >> 4;

    // loop-invariant per-lane bias/gain registers (colx = t*16+l15)
    float b1v[4], g1v[4], t1v[4], b2v[4], g2v[4], t2v[4];
    float c1v[4], cg1v[4], ct1v[4], w2v[4];
    #pragma unroll
    for (int t = 0; t < 4; t++) {
        int colx = t * 16 + l15;
        b1v[t] = eb1[colx];  g1v[t] = eg1[colx];  t1v[t] = ebt1[colx];
        b2v[t] = eb2[colx];  g2v[t] = eg2[colx];  t2v[t] = ebt2[colx];
        c1v[t] = cb1[colx];  cg1v[t] = cg1[colx]; ct1v[t] = cbt1[colx];
        w2v[t] = cW2[colx];
    }
    const float cb2s = cb2[0];

    __syncthreads();   // the ONLY barrier

    const int wv = blockIdx.x * 8 + wave;   // 0..8191
    const int ea = wv * 16 + l15;           // group a: gi = wv        (+k*16384)
    const int eb = (wv + 8192) * 16 + l15;  // group b: gi = wv + 8192 (+k*16384)

    #pragma unroll 1
    for (int k = 0; k < 2; ++k) {           // k=0: branch A; k=1: branch B
        const unsigned short* hb = k ? hbB : hbA;
        const unsigned short* efb = k ? efbB : efbA;
        const int* src = k ? srcB : srcA;
        const int* dst = k ? dstB : dstA;
        const int* pos = k ? posB : posA;
        const float* xrb = k ? xrbB : xrbA;
        const unsigned short* rbfb = k ? rbfbB : rbfbA;
        unsigned short* msgbuf = k ? msgbufB : msgbufA;
        float* xup = k ? xupB : xupA;

        const int s_a = src[ea], d_a = dst[ea], slot_a = pos[ea];
        const int s_b = src[eb], d_b = dst[eb], slot_b = pos[eb];
        const float xr_a = (g < 3) ? xrb[(size_t)ea * 3 + g] : 0.0f;
        const float xr_b = (g < 3) ? xrb[(size_t)eb * 3 + g] : 0.0f;

        float xa[4][4], xb[4][4];
        EDGE_FRONT(ea, s_a, d_a, xa);
        EDGE_FRONT(eb, s_b, d_b, xb);
        EDGE_BACK(xa, slot_a, d_a, xr_a);
        EDGE_BACK(xb, slot_b, d_b, xr_b);
    }
}

// ---------------------------------------------------------------------------
// Gather-reduce over CSR-ordered msgbuf. Vectorized: lane (r8,c8) loads
// bf16x8 (16 B); 8 rows per step; shfl_xor(8/16/32) column reduce.
__global__ __launch_bounds__(256, 4) void gather_kernel(
    const int* __restrict__ rowptrA, const int* __restrict__ rowptrB,
    const unsigned short* __restrict__ msgbufA, const unsigned short* __restrict__ msgbufB,
    float* __restrict__ aggrA, float* __restrict__ aggrB)
{
    const int tid = threadIdx.x;
    const int wave = tid >> 6, lane = tid & 63;
    const int r8 = lane >> 3, c8 = lane & 7;
    const int nwaves = gridDim.x * 4;
    for (int u = blockIdx.x * 4 + wave; u < 16384; u += nwaves) {
        const int br = u >> 13;
        const int n = u & 8191;
        const int* rowptr = br ? rowptrB : rowptrA;
        const unsigned short* mb = br ? msgbufB : msgbufA;
        float* aggr = br ? aggrB : aggrA;
        int base = rowptr[n];
        int deg = rowptr[n + 1] - base;
        float a[8];
        #pragma unroll
        for (int j = 0; j < 8; j++) a[j] = 0.f;
        int i = 0;
        for (; i + 8 <= deg; i += 8) {
            bf16x8 v = *(const bf16x8*)(mb + (size_t)(base + i + r8) * 64 + c8 * 8);
            #pragma unroll
            for (int j = 0; j < 8; j++) a[j] += bf2f((unsigned short)v[j]);
        }
        int rem = deg - i;
        if (r8 < rem) {
            bf16x8 v = *(const bf16x8*)(mb + (size_t)(base + i + r8) * 64 + c8 * 8);
            #pragma unroll
            for (int j = 0; j < 8; j++) a[j] += bf2f((unsigned short)v[j]);
        }
        #pragma unroll
        for (int j = 0; j < 8; j++) {
            a[j] += __shfl_xor(a[j], 8);
            a[j] += __shfl_xor(a[j], 16);
            a[j] += __shfl_xor(a[j], 32);
        }
        if (r8 == 0) {
            float inv = 1.0f / fmaxf((float)deg, 1.0f);
            float4 w0 = make_float4(a[0] * inv, a[1] * inv, a[2] * inv, a[3] * inv);
            float4 w1 = make_float4(a[4] * inv, a[5] * inv, a[6] * inv, a[7] * inv);
            *(float4*)(aggr + (size_t)n * 64 + c8 * 8) = w0;
            *(float4*)(aggr + (size_t)n * 64 + c8 * 8 + 4) = w1;
        }
    }
}

// ---------------------------------------------------------------------------
__global__ __launch_bounds__(256, 2) void qkv_kernel(
    const unsigned short* __restrict__ hbA, const unsigned short* __restrict__ hbB,
    const float* __restrict__ qW, const float* __restrict__ kW,
    const float* __restrict__ vW,
    unsigned short* __restrict__ qo, unsigned short* __restrict__ ko,
    unsigned short* __restrict__ vTo)
{
    __shared__ __attribute__((aligned(16))) short Wq[64 * 72];
    __shared__ __attribute__((aligned(16))) short Wk[64 * 72];
    __shared__ __attribute__((aligned(16))) short Wv[64 * 72];
    const int tid = threadIdx.x;
    for (int i = tid; i < 4096; i += 256) {
        int n = i >> 6, kk = i & 63;
        Wq[n * 72 + kk] = (short)f2bf(qW[kk * 64 + n]);
        Wk[n * 72 + kk] = (short)f2bf(kW[kk * 64 + n]);
        Wv[n * 72 + kk] = (short)f2bf(vW[kk * 64 + n]);
    }
    __syncthreads();
    const int wave = tid >> 6, lane = tid & 63, l15 = lane & 15, g = lane >> 4;
    const int row0 = blockIdx.x * 64 + wave * 16;
    bf16x8 aA[2], aB[2];
    aA[0] = *(const bf16x8*)(hbA + (size_t)(row0 + l15) * 64 + 8 * g);
    aA[1] = *(const bf16x8*)(hbA + (size_t)(row0 + l15) * 64 + 32 + 8 * g);
    aB[0] = *(const bf16x8*)(hbB + (size_t)(row0 + l15) * 64 + 8 * g);
    aB[1] = *(const bf16x8*)(hbB + (size_t)(row0 + l15) * 64 + 32 + 8 * g);
    floatx4 aq[4], ak4[4], av[4];
    #pragma unroll
    for (int t = 0; t < 4; t++) { aq[t] = (floatx4)0.0f; ak4[t] = (floatx4)0.0f; av[t] = (floatx4)0.0f; }
    #pragma unroll
    for (int c = 0; c < 2; c++) {
        #pragma unroll
        for (int t = 0; t < 4; t++) {
            int wo = (t * 16 + l15) * 72 + 32 * c + 8 * g;
            aq[t] = MFMA16(aA[c], *(const bf16x8*)(&Wq[wo]), aq[t]);
            ak4[t] = MFMA16(aB[c], *(const bf16x8*)(&Wk[wo]), ak4[t]);
            av[t] = MFMA16(aB[c], *(const bf16x8*)(&Wv[wo]), av[t]);
        }
    }
    #pragma unroll
    for (int t = 0; t < 4; t++) {
        #pragma unroll
        for (int r = 0; r < 4; r++) {
            int orow = row0 + 4 * g + r, ocol = t * 16 + l15;
            qo[(size_t)orow * 64 + ocol] = f2bf(lrelu(aq[t][r]));
            ko[(size_t)orow * 64 + ocol] = f2bf(lrelu(ak4[t][r]));
            vTo[(size_t)ocol * 8192 + orow] = f2bf(av[t][r]);   // v transposed
        }
    }
}

// ---------------------------------------------------------------------------
// Flash attention, K-split=8, direct L2 b-frag loads, no barriers.
__global__ __launch_bounds__(256, 4) void attn_kernel(
    const unsigned short* __restrict__ qb_, const unsigned short* __restrict__ kb_,
    const unsigned short* __restrict__ vT,
    float* __restrict__ Opart, float* __restrict__ ml)
{
    __shared__ __attribute__((aligned(16))) short pbuf[4][16 * 72];
    const int tid = threadIdx.x;
    const int wave = tid >> 6, lane = tid & 63, l15 = lane & 15, g = lane >> 4;
    const int qblock = blockIdx.x >> 3;         // 128 q-blocks
    const int split = blockIdx.x & 7;           // 8 k-splits
    const int qrow0 = qblock * 64 + wave * 16;
    const int kbase = split * 1024;
    bf16x8 qf[2];
    qf[0] = *(const bf16x8*)(qb_ + (size_t)(qrow0 + l15) * 64 + 8 * g);
    qf[1] = *(const bf16x8*)(qb_ + (size_t)(qrow0 + l15) * 64 + 32 + 8 * g);
    float m_[4], l_[4];
    floatx4 oacc[4];
    #pragma unroll
    for (int r = 0; r < 4; r++) { m_[r] = -1.0e30f; l_[r] = 0.f; }
    #pragma unroll
    for (int t = 0; t < 4; t++) oacc[t] = (floatx4)0.0f;

    for (int kt = 0; kt < 16; kt++) {
        const int krow0 = kbase + kt * 64;
        floatx4 sacc[4];
        #pragma unroll
        for (int t = 0; t < 4; t++) sacc[t] = (floatx4)0.0f;
        #pragma unroll
        for (int c = 0; c < 2; c++) {
            #pragma unroll
            for (int t = 0; t < 4; t++) {
                bf16x8 b = *(const bf16x8*)(kb_ + (size_t)(krow0 + t * 16 + l15) * 64 + 32 * c + 8 * g);
                sacc[t] = MFMA16(qf[c], b, sacc[t]);
            }
        }
        #pragma unroll
        for (int r = 0; r < 4; r++) {
            float mx = fmaxf(fmaxf(sacc[0][r], sacc[1][r]), fmaxf(sacc[2][r], sacc[3][r]));
            mx = rowmax16(mx);
            float mn = fmaxf(m_[r], mx);
            float sc = __expf(fminf(m_[r] - mn, 0.f));
            float ps = 0.f;
            int rowoff = (4 * g + r) * 72;
            #pragma unroll
            for (int t = 0; t < 4; t++) {
                float p = __expf(fminf(sacc[t][r] - mn, 0.f));
                ps += p;
                pbuf[wave][rowoff + t * 16 + l15] = (short)f2bf(p);
            }
            ps = rowsum16(ps);
            l_[r] = l_[r] * sc + ps;
            m_[r] = mn;
            #pragma unroll
            for (int t = 0; t < 4; t++) oacc[t][r] *= sc;
        }
        bf16x8 pf[2];
        pf[0] = *(const bf16x8*)(&pbuf[wave][l15 * 72 + 8 * g]);
        pf[1] = *(const bf16x8*)(&pbuf[wave][l15 * 72 + 32 + 8 * g]);
        #pragma unroll
        for (int c = 0; c < 2; c++) {
            #pragma unroll
            for (int t = 0; t < 4; t++) {
                bf16x8 b = *(const bf16x8*)(vT + (size_t)(t * 16 + l15) * 8192 + krow0 + 32 * c + 8 * g);
                oacc[t] = MFMA16(pf[c], b, oacc[t]);
            }
        }
    }
    #pragma unroll
    for (int t = 0; t < 4; t++) {
        #pragma unroll
        for (int r = 0; r < 4; r++) {
            int row = qrow0 + 4 * g + r;
            Opart[((size_t)split * 8192 + row) * 64 + t * 16 + l15] = oacc[t][r];
        }
    }
    if (l15 == 0) {
        #pragma unroll
        for (int r = 0; r < 4; r++) {
            int row = qrow0 + 4 * g + r;
            ml[((size_t)split * 8192 + row) * 2 + 0] = m_[r];
            ml[((size_t)split * 8192 + row) * 2 + 1] = l_[r];
        }
    }
}

__global__ void combine_kernel(const float* __restrict__ Opart, const float* __restrict__ ml,
                               unsigned short* __restrict__ attb)
{
    int idx = blockIdx.x * 256 + threadIdx.x;   // 8192*64
    int row = idx >> 6, col = idx & 63;
    float mm = -1.0e30f;
    #pragma unroll
    for (int s = 0; s < 8; s++) mm = fmaxf(mm, ml[((size_t)s * 8192 + row) * 2]);
    float l = 0.f, o = 0.f;
    #pragma unroll
    for (int s = 0; s < 8; s++) {
        float w = __expf(ml[((size_t)s * 8192 + row) * 2] - mm);
        l += w * ml[((size_t)s * 8192 + row) * 2 + 1];
        o += w * Opart[((size_t)s * 8192 + row) * 64 + col];
    }
    attb[(size_t)row * 64 + col] = f2bf(o / l);
}

// ---------------------------------------------------------------------------
__global__ __launch_bounds__(256, 2) void node_kernel(
    const float* __restrict__ hA, const float* __restrict__ hB,
    const float* __restrict__ origA, const float* __restrict__ origB,
    const unsigned short* __restrict__ attb,
    const float* __restrict__ aggrA, const float* __restrict__ aggrB,
    const float* __restrict__ nW1, const float* __restrict__ nb1,
    const float* __restrict__ ng1, const float* __restrict__ nbt1,
    const float* __restrict__ nW2, const float* __restrict__ nb2,
    const float* __restrict__ ng2, const float* __restrict__ nbt2,
    float* __restrict__ out)
{
    __shared__ __attribute__((aligned(16))) short W1t[64 * 264];
    __shared__ __attribute__((aligned(16))) short W2t[64 * 72];
    __shared__ __attribute__((aligned(16))) float pb[6 * 64];
    __shared__ __attribute__((aligned(16))) short ubuf[4][16 * 72];
    const int tid = threadIdx.x;
    for (int i = tid; i < 64 * 256; i += 256) {
        int n = i >> 8, kk = i & 255;
        W1t[n * 264 + kk] = (short)f2bf(nW1[kk * 64 + n]);
    }
    for (int i = tid; i < 4096; i += 256) {
        int n = i >> 6, kk = i & 63;
        W2t[n * 72 + kk] = (short)f2bf(nW2[kk * 64 + n]);
    }
    if (tid < 64) {
        pb[tid]       = nb1[tid];
        pb[64 + tid]  = ng1[tid];
        pb[128 + tid] = nbt1[tid];
        pb[192 + tid] = nb2[tid];
        pb[256 + tid] = ng2[tid];
        pb[320 + tid] = nbt2[tid];
    }
    __syncthreads();   // only barrier
    const int wave = tid >> 6, lane = tid & 63, l15 = lane & 15, g = lane >> 4;
    const int unit = blockIdx.x * 4 + wave;          // 1024 units
    const int br = unit >> 9;
    const int nb_ = (unit & 511) * 16;
    const float* h = br ? hB : hA;
    const float* orig = br ? origB : origA;
    const float* aggr = br ? aggrB : aggrA;
    const size_t outbase = br ? 573440 : 24576;

    const int row = nb_ + l15;

    bf16x8 af[8];
    af[0] = cvt8(h + (size_t)row * 64 + 8 * g);
    af[1] = cvt8(h + (size_t)row * 64 + 32 + 8 * g);
    af[2] = cvt8(aggr + (size_t)row * 64 + 8 * g);
    af[3] = cvt8(aggr + (size_t)row * 64 + 32 + 8 * g);
    if (br == 0) {
        af[4] = *(const bf16x8*)(attb + (size_t)row * 64 + 8 * g);
        af[5] = *(const bf16x8*)(attb + (size_t)row * 64 + 32 + 8 * g);
    } else {
        af[4] = (bf16x8)0;
        af[5] = (bf16x8)0;
    }
    af[6] = cvt8(orig + (size_t)row * 64 + 8 * g);
    af[7] = cvt8(orig + (size_t)row * 64 + 32 + 8 * g);

    floatx4 acc1[4];
    #pragma unroll
    for (int t = 0; t < 4; t++) acc1[t] = (floatx4)0.0f;
    #pragma unroll
    for (int c = 0; c < 8; c++) {
        #pragma unroll
        for (int t = 0; t < 4; t++) {
            bf16x8 b = *(const bf16x8*)(&W1t[(t * 16 + l15) * 264 + 32 * c + 8 * g]);
            acc1[t] = MFMA16(af[c], b, acc1[t]);
        }
    }
    float vv[4][4];
    #pragma unroll
    for (int t = 0; t < 4; t++)
        #pragma unroll
        for (int r = 0; r < 4; r++) vv[t][r] = acc1[t][r] + pb[t * 16 + l15];
    #pragma unroll
    for (int r = 0; r < 4; r++) {
        float s1 = vv[0][r] + vv[1][r] + vv[2][r] + vv[3][r];
        float s2 = vv[0][r] * vv[0][r] + vv[1][r] * vv[1][r] + vv[2][r] * vv[2][r] + vv[3][r] * vv[3][r];
        s1 = rowsum16(s1);
        s2 = rowsum16(s2);
        float mean = s1 * 0.015625f;
        float rstd = ln_rstd(s2, mean);
        int rowoff = (4 * g + r) * 72;
        #pragma unroll
        for (int t = 0; t < 4; t++) {
            int colx = t * 16 + l15;
            float x = (vv[t][r] - mean) * rstd * pb[64 + colx] + pb[128 + colx];
            x = lrelu(x);
            ubuf[wave][rowoff + colx] = (short)f2bf(x);
        }
    }
    bf16x8 a2[2];
    a2[0] = *(const bf16x8*)(&ubuf[wave][l15 * 72 + 8 * g]);
    a2[1] = *(const bf16x8*)(&ubuf[wave][l15 * 72 + 32 + 8 * g]);
    floatx4 acc2[4];
    #pragma unroll
    for (int t = 0; t < 4; t++) acc2[t] = (floatx4)0.0f;
    #pragma unroll
    for (int c = 0; c < 2; c++) {
        #pragma unroll
        for (int t = 0; t < 4; t++) {
            bf16x8 b = *(const bf16x8*)(&W2t[(t * 16 + l15) * 72 + 32 * c + 8 * g]);
            acc2[t] = MFMA16(a2[c], b, acc2[t]);
        }
    }
    float u2[4][4];
    #pragma unroll
    for (int t = 0; t < 4; t++)
        #pragma unroll
        for (int r = 0; r < 4; r++) u2[t][r] = acc2[t][r] + pb[192 + t * 16 + l15];
    #pragma unroll
    for (int r = 0; r < 4; r++) {
        float s1 = u2[0][r] + u2[1][r] + u2[2][r] + u2[3][r];
        float s2 = u2[0][r] * u2[0][r] + u2[1][r] * u2[1][r] + u2[2][r] * u2[2][r] + u2[3][r] * u2[3][r];
        s1 = rowsum16(s1);
        s2 = rowsum16(s2);
        float mean = s1 * 0.015625f;
        float rstd = ln_rstd(s2, mean);
        #pragma unroll
        for (int t = 0; t < 4; t++) {
            int colx = t * 16 + l15;
            float u = (u2[t][r] - mean) * rstd * pb[256 + colx] + pb[320 + colx];
            size_t orow = (size_t)(nb_ + 4 * g + r);
            float hh = h[orow * 64 + colx];
            out[outbase + orow * 64 + colx] = 0.5f * u + 0.5f * hh;
        }
    }
}

// ---------------------------------------------------------------------------
__global__ void xnew_kernel(
    const float* __restrict__ coordsA, const float* __restrict__ origcA,
    const float* __restrict__ coordsB, const float* __restrict__ origcB,
    const float* __restrict__ xupA, const float* __restrict__ xupB,
    const int* __restrict__ rowptrA, const int* __restrict__ rowptrB,
    float* __restrict__ out)
{
    int i = blockIdx.x * 256 + threadIdx.x;   // 49152 total
    int br = (i >= 24576) ? 1 : 0;
    int j = i - br * 24576;
    const float* coords = br ? coordsB : coordsA;
    const float* origc = br ? origcB : origcA;
    const float* xup = br ? xupB : xupA;
    const int* rp = br ? rowptrB : rowptrA;
    int node = j / 3;
    float cnt = (float)(rp[node + 1] - rp[node]);
    float val = 0.25f * origc[j] + 0.75f * coords[j] + xup[j] / fmaxf(cnt, 1.0f);
    out[(br ? 548864 : 0) + j] = val;
}

// ---------------------------------------------------------------------------
extern "C" void kernel_launch(void* const* d_in, const int* in_sizes, int n_in,
                              void* d_out, int out_size, void* d_ws, size_t ws_size,
                              hipStream_t stream)
{
    int base = n_in - 29;
    for (int i = 0; i < n_in; i++) {
        if (in_sizes[i] == 11200) { base = i; break; }
    }
    const float* coordsA = (const float*)d_in[0];
    const float* hA      = (const float*)d_in[1];
    const float* origA   = (const float*)d_in[2];
    const float* origcA  = (const float*)d_in[3];
    const float* efA     = (const float*)d_in[4];
    const float* coordsB = (const float*)d_in[5];
    const float* hB      = (const float*)d_in[6];
    const float* origB   = (const float*)d_in[7];
    const float* origcB  = (const float*)d_in[8];
    const float* efB     = (const float*)d_in[9];
    const float* P[25];
    for (int k = 0; k < 25; k++) P[k] = (const float*)d_in[base + k];
    const int* srcA = (const int*)d_in[base + 25];
    const int* dstA = (const int*)d_in[base + 26];
    const int* srcB = (const int*)d_in[base + 27];
    const int* dstB = (const int*)d_in[base + 28];

    char* ws = (char*)d_ws;
    unsigned short* msgbufA = (unsigned short*)(ws + 0);          // 33.5 MB
    unsigned short* msgbufB = (unsigned short*)(ws + 33554432);   // 33.5 MB
    float* Opart  = (float*)(ws + 0);                             // 16 MB (reuse after gather)
    float* mlbuf  = (float*)(ws + 16777216);                      // 512 KB (reuse)
    unsigned short* hbA  = (unsigned short*)(ws + 67108864);      // 1 MB
    unsigned short* hbB  = (unsigned short*)(ws + 68157440);
    unsigned short* efbA = (unsigned short*)(ws + 69206016);      // 16 MB
    unsigned short* efbB = (unsigned short*)(ws + 85983232);
    float* aggrA  = (float*)(ws + 102760448);                     // 2 MB
    float* aggrB  = (float*)(ws + 104857600);
    unsigned short* qbuf = (unsigned short*)(ws + 106954752);     // 1 MB
    unsigned short* kbuf = (unsigned short*)(ws + 108003328);
    unsigned short* vTb  = (unsigned short*)(ws + 109051904);
    unsigned short* attb = (unsigned short*)(ws + 110100480);
    // zero region (one memset, 327,680 B): xupA,xupB,histA,histB,curA,curB
    float* xupA = (float*)(ws + 111149056);
    float* xupB = (float*)(ws + 111247360);
    int* histA  = (int*)(ws + 111345664);
    int* histB  = (int*)(ws + 111378432);
    int* curA   = (int*)(ws + 111411200);
    int* curB   = (int*)(ws + 111443968);
    int* rowptrA = (int*)(ws + 111476736);
    int* rowptrB = (int*)(ws + 111517696);
    int* posA   = (int*)(ws + 111558656);                          // 1 MB
    int* posB   = (int*)(ws + 112607232);                          // 1 MB
    float* xrbA = (float*)(ws + 117440512);                        // 3 MB
    float* xrbB = (float*)(ws + 120586240);                        // 3 MB
    unsigned short* rbfbA = (unsigned short*)(ws + 123731968);     // 8 MB
    unsigned short* rbfbB = (unsigned short*)(ws + 132120576);     // 8 MB
    float* out = (float*)d_out;

    hipMemsetAsync(ws + 111149056, 0, 327680, stream);

    prep_kernel<<<17408, 256, 0, stream>>>(hA, hB, efA, efB, hbA, hbB, efbA, efbB);

    edgeprep_kernel<<<2048, 256, 0, stream>>>(coordsA, srcA, dstA,
                                              coordsB, srcB, dstB,
                                              xrbA, xrbB, rbfbA, rbfbB);

    hist_kernel<<<1024, 256, 0, stream>>>(dstA, dstB, histA, histB);
    scan_kernel<<<2, 1024, 0, stream>>>(histA, histB, rowptrA, rowptrB);
    scatter_kernel<<<1024, 256, 0, stream>>>(dstA, dstB, rowptrA, rowptrB,
                                             curA, curB, posA, posB);

    edge_kernel<<<1024, 512, 0, stream>>>(
        hbA, efbA, srcA, dstA, posA, xrbA, rbfbA,
        hbB, efbB, srcB, dstB, posB, xrbB, rbfbB,
        P[0], P[1], P[2], P[3], P[4], P[5], P[6], P[7],
        P[19], P[20], P[21], P[22], P[23], P[24],
        msgbufA, msgbufB, xupA, xupB);

    gather_kernel<<<2048, 256, 0, stream>>>(rowptrA, rowptrB, msgbufA, msgbufB,
                                            aggrA, aggrB);

    qkv_kernel<<<128, 256, 0, stream>>>(hbA, hbB, P[8], P[9], P[10], qbuf, kbuf, vTb);

    attn_kernel<<<1024, 256, 0, stream>>>(qbuf, kbuf, vTb, Opart, mlbuf);
    combine_kernel<<<2048, 256, 0, stream>>>(Opart, mlbuf, attb);

    node_kernel<<<256, 256, 0, stream>>>(
        hA, hB, origA, origB, attb, aggrA, aggrB,
        P[11], P[12], P[13], P[14], P[15], P[16], P[17], P[18], out);

    xnew_kernel<<<192, 256, 0, stream>>>(
        coordsA, origcA, coordsB, origcB, xupA, xupB, rowptrA, rowptrB, out);
}